// Round 3
// baseline (152.507 us; speedup 1.0000x reference)
//
#include <hip/hip_runtime.h>
#include <math.h>

#define BB 32
#define LL 4096
#define DD 1024
#define CH 64   // l-subtile staged in LDS by k_gemm

// Kernel 1: dlT[l*BB + b] = dot(doc[b,l,:], W[l,:]) + bias[l]
// One 64-lane wave per (b,l) row. UNCHANGED from round 2 (attribution).
__global__ __launch_bounds__(256) void k_dot(const float* __restrict__ doc,
                                             const float* __restrict__ W,
                                             const float* __restrict__ bias,
                                             float* __restrict__ dlT) {
  const int wid  = (blockIdx.x * 256 + threadIdx.x) >> 6;  // [0, BB*LL)
  const int lane = threadIdx.x & 63;
  const int l = wid >> 5;
  const int b = wid & 31;

  const float4* dp = reinterpret_cast<const float4*>(doc) + ((size_t)(b * LL + l) << 8);
  const float4* wp = reinterpret_cast<const float4*>(W) + ((size_t)l << 8);

  float acc = 0.f;
#pragma unroll
  for (int it = 0; it < 4; ++it) {
    float4 a = dp[lane + it * 64];
    float4 w = wp[lane + it * 64];
    acc = fmaf(a.x, w.x, acc);
    acc = fmaf(a.y, w.y, acc);
    acc = fmaf(a.z, w.z, acc);
    acc = fmaf(a.w, w.w, acc);
  }
#pragma unroll
  for (int off = 32; off > 0; off >>= 1) acc += __shfl_down(acc, off);

  if (lane == 0) dlT[(l << 5) + b] = acc + bias[l];
}

// Kernel 2: part[s][b*LL + j] = sum_{l in chunk s} dlT[l*BB+b] * G[l*LL+j]
// Block = 256 threads = 4 waves. Thread owns 4 consecutive j (float4 G loads,
// 16 B/lane); wave w owns b-octet [8w, 8w+8) (2 LDS b128 broadcasts per il).
// unroll 8 -> 8 float4 G loads in flight per thread: cold-HBM latency hidden
// by outstanding-load depth, not TLP. G read exactly once (all 32 b in-block).
#define FMA4(A, ds) \
  A.x = fmaf(ds, g.x, A.x); A.y = fmaf(ds, g.y, A.y); \
  A.z = fmaf(ds, g.z, A.z); A.w = fmaf(ds, g.w, A.w);

__global__ __launch_bounds__(256, 4) void k_gemm(const float* __restrict__ dlT,
                                                 const float* __restrict__ G,
                                                 float* __restrict__ part,
                                                 int chunk_l) {
  __shared__ float sdl[CH * BB];    // 8 KB
  const int jt   = blockIdx.x & 15; // 16 j-tiles of 256 columns
  const int s    = blockIdx.x >> 4; // l-chunk
  const int lane = threadIdx.x & 63;
  const int w    = threadIdx.x >> 6;
  const int b0   = w << 3;                    // this wave's b-octet
  const int j0   = (jt << 8) + (lane << 2);   // this thread's 4 columns
  const int l0   = s * chunk_l;

  float4 acc[8];
#pragma unroll
  for (int b = 0; b < 8; ++b) acc[b] = make_float4(0.f, 0.f, 0.f, 0.f);

  for (int t0 = 0; t0 < chunk_l; t0 += CH) {
    // stage CH*BB = 2048 floats (8 KB), coalesced float4
    {
      const float4* src = reinterpret_cast<const float4*>(dlT + (size_t)(l0 + t0) * BB);
      float4* dst = reinterpret_cast<float4*>(sdl);
      dst[threadIdx.x]       = src[threadIdx.x];
      dst[256 + threadIdx.x] = src[256 + threadIdx.x];
    }
    __syncthreads();

    const float* gb = G + (size_t)(l0 + t0) * LL + j0;
#pragma unroll 8
    for (int il = 0; il < CH; ++il) {
      const float4 g   = *reinterpret_cast<const float4*>(gb + (size_t)il * LL);
      const float4 d01 = *reinterpret_cast<const float4*>(sdl + il * BB + b0);
      const float4 d23 = *reinterpret_cast<const float4*>(sdl + il * BB + b0 + 4);
      FMA4(acc[0], d01.x) FMA4(acc[1], d01.y) FMA4(acc[2], d01.z) FMA4(acc[3], d01.w)
      FMA4(acc[4], d23.x) FMA4(acc[5], d23.y) FMA4(acc[6], d23.z) FMA4(acc[7], d23.w)
    }
    __syncthreads();
  }

  float* po = part + (size_t)s * (BB * LL);
#pragma unroll
  for (int b = 0; b < 8; ++b)
    *reinterpret_cast<float4*>(po + (size_t)(b0 + b) * LL + j0) = acc[b];
}

// Kernel 3: out[i] = sigmoid(sum_s part[s][i])  — UNCHANGED from round 2.
__global__ __launch_bounds__(256) void k_reduce(const float* __restrict__ part,
                                                float* __restrict__ out,
                                                int nchunks) {
  const int i = blockIdx.x * 256 + threadIdx.x;  // [0, BB*LL)
  float s = 0.f;
#pragma unroll 8
  for (int c = 0; c < nchunks; ++c) s += part[(size_t)c * (BB * LL) + i];
  out[i] = 1.f / (1.f + expf(-s));
}

extern "C" void kernel_launch(void* const* d_in, const int* in_sizes, int n_in,
                              void* d_out, int out_size, void* d_ws, size_t ws_size,
                              hipStream_t stream) {
  const float* doc  = (const float*)d_in[0];  // [B, L, D]
  const float* W    = (const float*)d_in[1];  // [L, D]
  const float* bias = (const float*)d_in[2];  // [L]
  const float* G    = (const float*)d_in[3];  // [L, L]
  float* out = (float*)d_out;                 // [B, L]

  float* dlT = (float*)d_ws;                              // BB*LL floats = 512 KB
  const size_t dl_bytes  = (size_t)BB * LL * sizeof(float);
  const size_t per_chunk = (size_t)BB * LL * sizeof(float);
  float* part = (float*)((char*)d_ws + dl_bytes);

  // l-split: 64 chunks (1024 blocks, 4 blocks/CU) if workspace allows.
  int nchunks = 64;
  size_t avail = ws_size > dl_bytes ? (ws_size - dl_bytes) / per_chunk : 0;
  if ((size_t)nchunks > avail) {
    nchunks = 1;
    while ((size_t)(nchunks * 2) <= avail && nchunks * 2 <= 64) nchunks *= 2;
  }
  const int chunk_l = LL / nchunks;   // multiple of CH for nchunks <= 64

  k_dot<<<dim3((BB * LL) / 4), dim3(256), 0, stream>>>(doc, W, bias, dlT);
  k_gemm<<<dim3(16 * nchunks), dim3(256), 0, stream>>>(dlT, G, part, chunk_l);
  k_reduce<<<dim3((BB * LL) / 256), dim3(256), 0, stream>>>(part, out, nchunks);
}